// Round 8
// baseline (69.584 us; speedup 1.0000x reference)
//
#include <hip/hip_runtime.h>
#include <stdint.h>

// Problem constants (fixed shapes from the reference)
#define HEADS 8
#define DIM   512
#define HD    64
#define NE    16      // entities per sentence
#define NS    64      // sentences
#define NB    64      // batch

typedef short bf16x8 __attribute__((ext_vector_type(8)));
typedef float f32x4  __attribute__((ext_vector_type(4)));

__device__ __forceinline__ unsigned short f2bf(float f) {
    union { float f; uint32_t u; } v; v.f = f;
    uint32_t u = v.u;
    u += 0x7fffu + ((u >> 16) & 1u);   // RNE
    return (unsigned short)(u >> 16);
}

// pack fp32 -> bf16 via HW RNE converts (no builtin on gfx950 -> asm)
__device__ __forceinline__ uint32_t cvt2(float a, float b) {
    uint32_t r;
    asm("v_cvt_pk_bf16_f32 %0, %1, %2" : "=v"(r) : "v"(a), "v"(b));
    return r;
}
__device__ __forceinline__ uint2 cvt4(float4 v) {
    return (uint2){cvt2(v.x, v.y), cvt2(v.z, v.w)};
}
__device__ __forceinline__ uint2 cvt4f(f32x4 v) {
    return (uint2){cvt2(v.x, v.y), cvt2(v.z, v.w)};
}

// ---------------------------------------------------------------------------
// K0: u_bf[h][c] = bf16( sum_j qvec_h[j] * wk[h*64+j][c] ), 16 blocks.
// qvec_h computed in-block; pad rows h=8..15 zeroed (score MFMA reads 16 rows).
// q_h · bk_h is softmax-invariant -> bk unused.
// ---------------------------------------------------------------------------
__global__ __launch_bounds__(256) void k_prep(
    const float* __restrict__ qp, const float* __restrict__ wq,
    const float* __restrict__ bq, const float* __restrict__ wk,
    unsigned short* __restrict__ u_bf)
{
    const int bid = blockIdx.x;
    const int t = threadIdx.x;
    const int h = bid >> 1, ch = bid & 1;
    __shared__ float qs[HD];
    {   // qvec for head h: thread (j = t>>2, q = t&3) sums 128 elems
        const int j = t >> 2, q = t & 3;
        const float* w = wq + (size_t)(h * HD + j) * DIM + q * 128;
        const float* qq = qp + q * 128;
        float a = 0.f;
        #pragma unroll 8
        for (int i = 0; i < 128; i++) a += w[i] * qq[i];
        a += __shfl_xor(a, 1);
        a += __shfl_xor(a, 2);
        if (q == 0) qs[j] = a + bq[h * HD + j];
    }
    __syncthreads();
    const int c = ch * 256 + t;
    const float* w = wk + (size_t)(h * HD) * DIM + c;
    float acc = 0.f;
    #pragma unroll 8
    for (int j = 0; j < HD; j++) acc += qs[j] * w[(size_t)j * DIM];
    u_bf[h * DIM + c] = f2bf(acc);
    u_bf[(h + 8) * DIM + c] = 0;           // zero pad rows for MFMA N=16
}

// ---------------------------------------------------------------------------
// K1: fused score/softmax/weighted-aggregation.
// Block = (s, 2 batch slots): 2048 blocks, 32KB LDS, 3 blocks/CU.
//   stage:   thread (bb = t>>7, d4 = t&127) loads 16 entity float4 rows into
//            REGISTERS (16 outstanding coalesced loads), then cvt+ds_write
//            the bf16 copy for the score MFMA (byte swizzle ^ (e&7)<<4).
//   score:   waves 0,1 (b = w): 16-step MFMA chain over LDS A-frags +
//            global u_bf B-frags; softmax via 2 shuffles (e=4g+j, h=lane&15).
//   weighted: NO LDS re-read — each thread already holds its 16 float4 rows;
//            acc[8h][4d] fp32 FMA from registers + broadcast attn_s reads.
// ---------------------------------------------------------------------------
__global__ __launch_bounds__(256, 3) void k_attn(
    const float* __restrict__ ents, const unsigned short* __restrict__ u_bf,
    unsigned short* __restrict__ weighted)
{
    __shared__ unsigned short ent[2 * NE * DIM];   // 32 KB, swizzled bf16
    __shared__ float attn_s[2][NE][8];             // 1 KB
    const int t = threadIdx.x;
    const int bid = blockIdx.x;
    const int s = bid >> 5;
    const int bg = (bid & 31) << 1;
    const int w = t >> 6, lane = t & 63;
    const int bb = t >> 7, d4 = t & 127;

    // ---- stage: 16 reg loads (all outstanding), then bf16 LDS copy ----
    const float* p = ents + ((size_t)((s * NE) * NB + bg + bb) << 9) + (d4 << 2);
    float4 v[NE];
    #pragma unroll
    for (int e = 0; e < NE; e++)
        v[e] = *(const float4*)(p + (size_t)e * (NB * DIM));
    {
        const uint32_t dstb = (uint32_t)(t << 3);
        #pragma unroll
        for (int e = 0; e < NE; e++) {
            const uint2 hv = cvt4(v[e]);
            const uint32_t off = ((uint32_t)(e << 11) | dstb) ^ (uint32_t)((e & 7) << 4);
            *(uint2*)((char*)ent + off) = hv;
        }
    }
    __syncthreads();

    // ---- score MFMA + softmax (waves 0,1 handle b = bg + w) ----
    if (w < 2) {
        const int m = lane & 15, g = lane >> 4;
        const uint32_t swz = (uint32_t)((m & 7) << 4);
        const uint32_t rowb = (uint32_t)((m * 2 + w) << 10);
        const unsigned short* urow = u_bf + m * DIM + g * 8;
        f32x4 acc = {0.f, 0.f, 0.f, 0.f};
        #pragma unroll
        for (int ks = 0; ks < 16; ks++) {
            const int kp = g * 8 + ks * 32;
            const bf16x8 af = *(const bf16x8*)((const char*)ent + ((rowb + (uint32_t)(kp << 1)) ^ swz));
            const bf16x8 bf = *(const bf16x8*)(urow + ks * 32);
            acc = __builtin_amdgcn_mfma_f32_16x16x32_bf16(af, bf, acc, 0, 0, 0);
        }
        const float scale = 0.125f;   // 1/sqrt(64)
        float s0 = acc[0]*scale, s1 = acc[1]*scale, s2 = acc[2]*scale, s3 = acc[3]*scale;
        float mx = fmaxf(fmaxf(s0, s1), fmaxf(s2, s3));
        mx = fmaxf(mx, __shfl_xor(mx, 16));
        mx = fmaxf(mx, __shfl_xor(mx, 32));
        const float p0 = __expf(s0 - mx), p1 = __expf(s1 - mx);
        const float p2 = __expf(s2 - mx), p3 = __expf(s3 - mx);
        float sm = p0 + p1 + p2 + p3;
        sm += __shfl_xor(sm, 16);
        sm += __shfl_xor(sm, 32);
        const float inv = 1.f / sm;
        if (m < HEADS) {             // h = m
            attn_s[w][4 * g + 0][m] = p0 * inv;
            attn_s[w][4 * g + 1][m] = p1 * inv;
            attn_s[w][4 * g + 2][m] = p2 * inv;
            attn_s[w][4 * g + 3][m] = p3 * inv;
        }
    }
    __syncthreads();

    // ---- weighted sum: pure-register fp32 FMA, broadcast attn reads ----
    {
        f32x4 acc[HEADS];
        #pragma unroll
        for (int h = 0; h < HEADS; h++) acc[h] = (f32x4){0.f, 0.f, 0.f, 0.f};

        #pragma unroll
        for (int e = 0; e < NE; e++) {
            const f32x4 ev = {v[e].x, v[e].y, v[e].z, v[e].w};
            const f32x4 a0 = *(const f32x4*)&attn_s[bb][e][0];   // broadcast
            const f32x4 a1 = *(const f32x4*)&attn_s[bb][e][4];
            acc[0] += a0.x * ev; acc[1] += a0.y * ev;
            acc[2] += a0.z * ev; acc[3] += a0.w * ev;
            acc[4] += a1.x * ev; acc[5] += a1.y * ev;
            acc[6] += a1.z * ev; acc[7] += a1.w * ev;
        }
        const int sb = s * NB + bg + bb;
        unsigned short* wrow = weighted + ((size_t)sb << 12) + (d4 << 2);
        #pragma unroll
        for (int h = 0; h < HEADS; h++) {
            *(uint2*)(wrow + h * DIM) = cvt4f(acc[h]);
        }
    }
}

// ---------------------------------------------------------------------------
// K2/K3: C[M=4096, 64 cols per y] = A(bf16) @ B^T(fp32, cvt in staging) + bias
// BM=64, BN=64, BK=64; 4 waves, 16-row strip x 64 cols each.
// Register-prefetch double buffer: loads for tile k+1 issued before MFMA of k.
//   K2: A=weighted (lda 4096, col off 512*y=head), B=wv rows 64y.. -> ctx bf16
//   K3: A=ctx      (lda 512),                      B=wo rows 64y.. -> out f32
// ---------------------------------------------------------------------------
template <typename CT>
__global__ __launch_bounds__(256) void k_gemm(
    const unsigned short* __restrict__ A, int lda, int aOffY,
    const float* __restrict__ B, int ldb, int bOffY,
    const float* __restrict__ bias, CT* __restrict__ C, int ldc, int cOffY, int K)
{
    __shared__ unsigned short a_s[64][72];
    __shared__ unsigned short b_s[64][72];
    const int t = threadIdx.x;
    const int m0 = blockIdx.x * 64;
    const int y  = blockIdx.y;
    const int w = t >> 6, l = t & 63;
    const int m = l & 15, g = l >> 4;
    const int lr = t >> 2, lk = (t & 3) * 16;

    const unsigned short* Ap = A + (size_t)(m0 + lr) * lda + (size_t)aOffY * y + lk;
    const float* Bp = B + (size_t)(bOffY * y + lr) * ldb + lk;

    ushort4 av[4];
    float4  bv[4];
    #pragma unroll
    for (int i = 0; i < 4; i++) {
        av[i] = *(const ushort4*)(Ap + 4 * i);
        bv[i] = *(const float4*)(Bp + 4 * i);
    }

    f32x4 acc[4];
    #pragma unroll
    for (int i = 0; i < 4; i++) acc[i] = (f32x4){0.f, 0.f, 0.f, 0.f};

    for (int k0 = 0; k0 < K; k0 += 64) {
        #pragma unroll
        for (int i = 0; i < 4; i++) {
            *(ushort4*)&a_s[lr][lk + 4 * i] = av[i];
            const uint2 h = cvt4(bv[i]);
            *(uint2*)&b_s[lr][lk + 4 * i] = h;
        }
        __syncthreads();
        if (k0 + 64 < K) {
            #pragma unroll
            for (int i = 0; i < 4; i++) {
                av[i] = *(const ushort4*)(Ap + k0 + 64 + 4 * i);
                bv[i] = *(const float4*)(Bp + k0 + 64 + 4 * i);
            }
        }
        #pragma unroll
        for (int kk = 0; kk < 64; kk += 32) {
            const int kp = kk + g * 8;
            const bf16x8 af = *(const bf16x8*)&a_s[w * 16 + m][kp];
            const bf16x8 b0 = *(const bf16x8*)&b_s[ 0 + m][kp];
            const bf16x8 b1 = *(const bf16x8*)&b_s[16 + m][kp];
            const bf16x8 b2 = *(const bf16x8*)&b_s[32 + m][kp];
            const bf16x8 b3 = *(const bf16x8*)&b_s[48 + m][kp];
            acc[0] = __builtin_amdgcn_mfma_f32_16x16x32_bf16(af, b0, acc[0], 0, 0, 0);
            acc[1] = __builtin_amdgcn_mfma_f32_16x16x32_bf16(af, b1, acc[1], 0, 0, 0);
            acc[2] = __builtin_amdgcn_mfma_f32_16x16x32_bf16(af, b2, acc[2], 0, 0, 0);
            acc[3] = __builtin_amdgcn_mfma_f32_16x16x32_bf16(af, b3, acc[3], 0, 0, 0);
        }
        __syncthreads();
    }

    const int colbase = cOffY * y;
    #pragma unroll
    for (int nt = 0; nt < 4; nt++) {
        const int col = colbase + nt * 16 + m;
        const float bs = bias[col];
        #pragma unroll
        for (int j = 0; j < 4; j++) {
            const int row = m0 + w * 16 + g * 4 + j;
            const float val = acc[nt][j] + bs;
            if (sizeof(CT) == 2) {
                ((unsigned short*)C)[(size_t)row * ldc + col] = f2bf(val);
            } else {
                ((float*)C)[(size_t)row * ldc + col] = val;
            }
        }
    }
}

// ---------------------------------------------------------------------------
extern "C" void kernel_launch(void* const* d_in, const int* in_sizes, int n_in,
                              void* d_out, int out_size, void* d_ws, size_t ws_size,
                              hipStream_t stream)
{
    const float* ents = (const float*)d_in[0];
    const float* qp   = (const float*)d_in[1];
    const float* wq   = (const float*)d_in[2];
    const float* wk   = (const float*)d_in[3];
    const float* wv   = (const float*)d_in[4];
    const float* wo   = (const float*)d_in[5];
    const float* bq   = (const float*)d_in[6];
    // d_in[7] = bk: per-head softmax-invariant constant -> algebraically unused
    const float* bv   = (const float*)d_in[8];
    const float* bo   = (const float*)d_in[9];

    // workspace layout (~38 MB)
    char* ws = (char*)d_ws;
    unsigned short* u_bf     = (unsigned short*)ws;                        // 16 KB [16][512]
    unsigned short* weighted = (unsigned short*)(ws + 2097152);            // 32 MB [4096][4096]
    unsigned short* ctx      = (unsigned short*)(ws + 2097152 + 33554432); // 4 MB [4096][512]

    k_prep <<<16, 256, 0, stream>>>(qp, wq, bq, wk, u_bf);
    k_attn <<<2048, 256, 0, stream>>>(ents, u_bf, weighted);
    k_gemm<unsigned short><<<dim3(64, 8), 256, 0, stream>>>(
        weighted, HEADS * DIM, DIM, wv, DIM, HD, bv, ctx, DIM, HD, DIM);
    k_gemm<float><<<dim3(64, 8), 256, 0, stream>>>(
        ctx, DIM, 0, wo, DIM, HD, bo, (float*)d_out, DIM, HD, DIM);
}

// Round 9
// 62.029 us; speedup vs baseline: 1.1218x; 1.1218x over previous
//
#include <hip/hip_runtime.h>
#include <stdint.h>

// Problem constants (fixed shapes from the reference)
#define HEADS 8
#define DIM   512
#define HD    64
#define NE    16      // entities per sentence
#define NS    64      // sentences
#define NB    64      // batch

typedef short bf16x8 __attribute__((ext_vector_type(8)));
typedef float f32x4  __attribute__((ext_vector_type(4)));

__device__ __forceinline__ unsigned short f2bf(float f) {
    union { float f; uint32_t u; } v; v.f = f;
    uint32_t u = v.u;
    u += 0x7fffu + ((u >> 16) & 1u);   // RNE
    return (unsigned short)(u >> 16);
}
__device__ __forceinline__ float bf_lo(uint32_t u) {
    union { uint32_t u; float f; } v; v.u = u << 16; return v.f;
}
__device__ __forceinline__ float bf_hi(uint32_t u) {
    union { uint32_t u; float f; } v; v.u = u & 0xffff0000u; return v.f;
}

// pack fp32 -> bf16 via HW RNE converts (no builtin on gfx950 -> asm)
__device__ __forceinline__ uint32_t cvt2(float a, float b) {
    uint32_t r;
    asm("v_cvt_pk_bf16_f32 %0, %1, %2" : "=v"(r) : "v"(a), "v"(b));
    return r;
}
__device__ __forceinline__ uint2 cvt4(float4 v) {
    return (uint2){cvt2(v.x, v.y), cvt2(v.z, v.w)};
}

// ---------------------------------------------------------------------------
// K0: fused prep (528 blocks) — identical to R7 (proven at 65.2 µs).
//   blocks [0,16):    u_bf[h][c] = bf16( sum_j qvec_h[j] * wk[h*64+j][c] ),
//                     qvec_h computed in-block; rows 8..15 zeroed.
//   blocks [16,272):  wv -> bf16
//   blocks [272,528): wo -> bf16
// q_h · bk_h is softmax-invariant -> bk unused.
// ---------------------------------------------------------------------------
__global__ __launch_bounds__(256) void k_prep(
    const float* __restrict__ qp, const float* __restrict__ wq,
    const float* __restrict__ bq, const float* __restrict__ wk,
    const float* __restrict__ wv, const float* __restrict__ wo,
    unsigned short* __restrict__ u_bf,
    unsigned short* __restrict__ wv_bf, unsigned short* __restrict__ wo_bf)
{
    const int bid = blockIdx.x;
    const int t = threadIdx.x;
    if (bid < 16) {
        const int h = bid >> 1, ch = bid & 1;
        __shared__ float qs[HD];
        {   // qvec for head h: thread (j = t>>2, q = t&3) sums 128 elems
            const int j = t >> 2, q = t & 3;
            const float* w = wq + (size_t)(h * HD + j) * DIM + q * 128;
            const float* qq = qp + q * 128;
            float a = 0.f;
            #pragma unroll 8
            for (int i = 0; i < 128; i++) a += w[i] * qq[i];
            a += __shfl_xor(a, 1);
            a += __shfl_xor(a, 2);
            if (q == 0) qs[j] = a + bq[h * HD + j];
        }
        __syncthreads();
        const int c = ch * 256 + t;
        const float* w = wk + (size_t)(h * HD) * DIM + c;
        float acc = 0.f;
        #pragma unroll 8
        for (int j = 0; j < HD; j++) acc += qs[j] * w[(size_t)j * DIM];
        u_bf[h * DIM + c] = f2bf(acc);
        u_bf[(h + 8) * DIM + c] = 0;           // zero pad rows for MFMA N=16
        return;
    }
    const bool is_v = bid < 272;
    const float* src = is_v ? wv : wo;
    unsigned short* dst = is_v ? wv_bf : wo_bf;
    const int li = ((is_v ? bid - 16 : bid - 272) * 1024 + t * 4);
    const float4 v = *(const float4*)(src + li);
    ushort4 hv;
    hv.x = f2bf(v.x); hv.y = f2bf(v.y); hv.z = f2bf(v.z); hv.w = f2bf(v.w);
    *(ushort4*)(dst + li) = hv;
}

// ---------------------------------------------------------------------------
// K1: fused score/softmax/weighted-aggregation.
// Block = ONE (s,b): 4096 blocks, 16.5 KB LDS, launch_bounds(256,6)
//   -> 6 blocks/CU = 24 waves/CU (vs R7's 16): cross-block phase overlap.
//   stage:   8 iters/thread: coalesced float4 load + cvt_pk + ds_write_b64.
//            LDS row e (1KB), byte swizzle ^ (e&7)<<4.
//   score:   wave 0: 16-step MFMA chain (LDS A-frags + global u_bf B-frags);
//            softmax via 2 shuffles (e = 4g+j, h = lane&15).
//   weighted: all 4 waves, lane owns 2 d (4B LDS reads, 2-way = free);
//            16e x 8h x 2d FMA; packed bf16 store.
// ---------------------------------------------------------------------------
__global__ __launch_bounds__(256, 6) void k_attn(
    const float* __restrict__ ents, const unsigned short* __restrict__ u_bf,
    unsigned short* __restrict__ weighted)
{
    __shared__ unsigned short ent[NE * DIM];   // 16 KB, swizzled bf16
    __shared__ float attn_s[NE][8];            // 512 B
    const int t = threadIdx.x;
    const int bid = blockIdx.x;                // 0..4095
    const int s = bid >> 6, b = bid & 63;

    // ---- stage: iter i covers entity rows 2i, 2i+1 (4KB per 256 threads) ----
    {
        const float* base = ents + ((size_t)(s * NE) * NB + b) * DIM;
        #pragma unroll
        for (int i = 0; i < 8; i++) {
            const int c = t + 256 * i;          // 0..2047 float4-chunks
            const int e = c >> 7, d4 = c & 127;
            const float4 v = *(const float4*)(base + (size_t)e * (NB * DIM) + (d4 << 2));
            const uint2 hv = cvt4(v);
            const uint32_t off = (uint32_t)((e << 10) | (d4 << 3)) ^ (uint32_t)((e & 7) << 4);
            *(uint2*)((char*)ent + off) = hv;
        }
    }
    __syncthreads();

    // ---- score MFMA + softmax (wave 0 only; other waves' blocks overlap) ----
    if (t < 64) {
        const int m = t & 15, g = t >> 4;
        const uint32_t swz = (uint32_t)((m & 7) << 4);
        const uint32_t rowb = (uint32_t)(m << 10);
        const unsigned short* urow = u_bf + m * DIM + g * 8;
        f32x4 acc = {0.f, 0.f, 0.f, 0.f};
        #pragma unroll
        for (int ks = 0; ks < 16; ks++) {
            const int kp = g * 8 + ks * 32;
            const bf16x8 af = *(const bf16x8*)((const char*)ent + ((rowb + (uint32_t)(kp << 1)) ^ swz));
            const bf16x8 bf = *(const bf16x8*)(urow + ks * 32);
            acc = __builtin_amdgcn_mfma_f32_16x16x32_bf16(af, bf, acc, 0, 0, 0);
        }
        const float scale = 0.125f;   // 1/sqrt(64)
        float s0 = acc[0]*scale, s1 = acc[1]*scale, s2 = acc[2]*scale, s3 = acc[3]*scale;
        float mx = fmaxf(fmaxf(s0, s1), fmaxf(s2, s3));
        mx = fmaxf(mx, __shfl_xor(mx, 16));
        mx = fmaxf(mx, __shfl_xor(mx, 32));
        const float p0 = __expf(s0 - mx), p1 = __expf(s1 - mx);
        const float p2 = __expf(s2 - mx), p3 = __expf(s3 - mx);
        float sm = p0 + p1 + p2 + p3;
        sm += __shfl_xor(sm, 16);
        sm += __shfl_xor(sm, 32);
        const float inv = 1.f / sm;
        if (m < HEADS) {             // h = m
            attn_s[4 * g + 0][m] = p0 * inv;
            attn_s[4 * g + 1][m] = p1 * inv;
            attn_s[4 * g + 2][m] = p2 * inv;
            attn_s[4 * g + 3][m] = p3 * inv;
        }
    }
    __syncthreads();

    // ---- weighted sum: lane owns d0 = 2t (2 d x 8 heads) ----
    {
        const int d0 = t << 1;
        float accx[HEADS], accy[HEADS];
        #pragma unroll
        for (int h = 0; h < HEADS; h++) { accx[h] = 0.f; accy[h] = 0.f; }

        #pragma unroll
        for (int e = 0; e < NE; e++) {
            const uint32_t off = (uint32_t)((e << 10) | (d0 << 1)) ^ (uint32_t)((e & 7) << 4);
            const uint32_t rv = *(const uint32_t*)((const char*)ent + off);
            const float ev0 = bf_lo(rv), ev1 = bf_hi(rv);
            const f32x4 a0 = *(const f32x4*)&attn_s[e][0];   // broadcast
            const f32x4 a1 = *(const f32x4*)&attn_s[e][4];
            accx[0] += a0.x * ev0; accy[0] += a0.x * ev1;
            accx[1] += a0.y * ev0; accy[1] += a0.y * ev1;
            accx[2] += a0.z * ev0; accy[2] += a0.z * ev1;
            accx[3] += a0.w * ev0; accy[3] += a0.w * ev1;
            accx[4] += a1.x * ev0; accy[4] += a1.x * ev1;
            accx[5] += a1.y * ev0; accy[5] += a1.y * ev1;
            accx[6] += a1.z * ev0; accy[6] += a1.z * ev1;
            accx[7] += a1.w * ev0; accy[7] += a1.w * ev1;
        }
        unsigned short* wrow = weighted + ((size_t)bid << 12) + d0;
        #pragma unroll
        for (int h = 0; h < HEADS; h++) {
            *(uint32_t*)(wrow + h * DIM) = cvt2(accx[h], accy[h]);
        }
    }
}

// ---------------------------------------------------------------------------
// K2/K3: C[M=4096, 64 cols per y] = A(bf16) @ B^T(bf16) + bias
// BM=64, BN=64, BK=64; 4 waves, 16-row strip x 64 cols each. (R7-proven.)
//   K2: A=weighted (lda 4096, col off 512*y=head), B=wv_bf rows 64y.. -> ctx bf16
//   K3: A=ctx      (lda 512),                      B=wo_bf rows 64y.. -> out f32
// ---------------------------------------------------------------------------
template <typename CT>
__global__ __launch_bounds__(256) void k_gemm(
    const unsigned short* __restrict__ A, int lda, int aOffY,
    const unsigned short* __restrict__ B, int ldb, int bOffY,
    const float* __restrict__ bias, CT* __restrict__ C, int ldc, int cOffY, int K)
{
    __shared__ unsigned short a_s[64][72];
    __shared__ unsigned short b_s[64][72];
    const int t = threadIdx.x;
    const int m0 = blockIdx.x * 64;
    const int y  = blockIdx.y;
    const int w = t >> 6, l = t & 63;
    const int m = l & 15, g = l >> 4;
    const int lr = t >> 2, lk = (t & 3) * 16;

    const unsigned short* Ap = A + (size_t)(m0 + lr) * lda + (size_t)aOffY * y;
    const unsigned short* Bp = B + (size_t)(bOffY * y + lr) * ldb;

    f32x4 acc[4];
    #pragma unroll
    for (int i = 0; i < 4; i++) acc[i] = (f32x4){0.f, 0.f, 0.f, 0.f};

    for (int k0 = 0; k0 < K; k0 += 64) {
        const ushort4 av0 = *(const ushort4*)(Ap + k0 + lk);
        const ushort4 av1 = *(const ushort4*)(Ap + k0 + lk + 4);
        const ushort4 av2 = *(const ushort4*)(Ap + k0 + lk + 8);
        const ushort4 av3 = *(const ushort4*)(Ap + k0 + lk + 12);
        const ushort4 bv0 = *(const ushort4*)(Bp + k0 + lk);
        const ushort4 bv1 = *(const ushort4*)(Bp + k0 + lk + 4);
        const ushort4 bv2 = *(const ushort4*)(Bp + k0 + lk + 8);
        const ushort4 bv3 = *(const ushort4*)(Bp + k0 + lk + 12);
        *(ushort4*)&a_s[lr][lk]      = av0;
        *(ushort4*)&a_s[lr][lk + 4]  = av1;
        *(ushort4*)&a_s[lr][lk + 8]  = av2;
        *(ushort4*)&a_s[lr][lk + 12] = av3;
        *(ushort4*)&b_s[lr][lk]      = bv0;
        *(ushort4*)&b_s[lr][lk + 4]  = bv1;
        *(ushort4*)&b_s[lr][lk + 8]  = bv2;
        *(ushort4*)&b_s[lr][lk + 12] = bv3;
        __syncthreads();
        #pragma unroll
        for (int kk = 0; kk < 64; kk += 32) {
            const int kp = kk + g * 8;
            const bf16x8 af = *(const bf16x8*)&a_s[w * 16 + m][kp];
            const bf16x8 b0 = *(const bf16x8*)&b_s[ 0 + m][kp];
            const bf16x8 b1 = *(const bf16x8*)&b_s[16 + m][kp];
            const bf16x8 b2 = *(const bf16x8*)&b_s[32 + m][kp];
            const bf16x8 b3 = *(const bf16x8*)&b_s[48 + m][kp];
            acc[0] = __builtin_amdgcn_mfma_f32_16x16x32_bf16(af, b0, acc[0], 0, 0, 0);
            acc[1] = __builtin_amdgcn_mfma_f32_16x16x32_bf16(af, b1, acc[1], 0, 0, 0);
            acc[2] = __builtin_amdgcn_mfma_f32_16x16x32_bf16(af, b2, acc[2], 0, 0, 0);
            acc[3] = __builtin_amdgcn_mfma_f32_16x16x32_bf16(af, b3, acc[3], 0, 0, 0);
        }
        __syncthreads();
    }

    const int colbase = cOffY * y;
    #pragma unroll
    for (int nt = 0; nt < 4; nt++) {
        const int col = colbase + nt * 16 + m;
        const float bs = bias[col];
        #pragma unroll
        for (int j = 0; j < 4; j++) {
            const int row = m0 + w * 16 + g * 4 + j;
            const float val = acc[nt][j] + bs;
            if (sizeof(CT) == 2) {
                ((unsigned short*)C)[(size_t)row * ldc + col] = f2bf(val);
            } else {
                ((float*)C)[(size_t)row * ldc + col] = val;
            }
        }
    }
}

// ---------------------------------------------------------------------------
extern "C" void kernel_launch(void* const* d_in, const int* in_sizes, int n_in,
                              void* d_out, int out_size, void* d_ws, size_t ws_size,
                              hipStream_t stream)
{
    const float* ents = (const float*)d_in[0];
    const float* qp   = (const float*)d_in[1];
    const float* wq   = (const float*)d_in[2];
    const float* wk   = (const float*)d_in[3];
    const float* wv   = (const float*)d_in[4];
    const float* wo   = (const float*)d_in[5];
    const float* bq   = (const float*)d_in[6];
    // d_in[7] = bk: per-head softmax-invariant constant -> algebraically unused
    const float* bv   = (const float*)d_in[8];
    const float* bo   = (const float*)d_in[9];

    // workspace layout (~40 MB)
    char* ws = (char*)d_ws;
    unsigned short* u_bf     = (unsigned short*)ws;                        // 16 KB [16][512]
    unsigned short* wv_bf    = (unsigned short*)(ws + 65536);              // 512 KB
    unsigned short* wo_bf    = (unsigned short*)(ws + 65536 + 524288);     // 512 KB
    unsigned short* weighted = (unsigned short*)(ws + 2097152);            // 32 MB [4096][4096]
    unsigned short* ctx      = (unsigned short*)(ws + 2097152 + 33554432); // 4 MB [4096][512]

    k_prep <<<528, 256, 0, stream>>>(qp, wq, bq, wk, wv, wo, u_bf, wv_bf, wo_bf);
    k_attn <<<4096, 256, 0, stream>>>(ents, u_bf, weighted);
    k_gemm<unsigned short><<<dim3(64, 8), 256, 0, stream>>>(
        weighted, HEADS * DIM, DIM, wv_bf, DIM, HD, bv, ctx, DIM, HD, DIM);
    k_gemm<float><<<dim3(64, 8), 256, 0, stream>>>(
        ctx, DIM, 0, wo_bf, DIM, HD, bo, (float*)d_out, DIM, HD, DIM);
}